// Round 13
// baseline (1604.607 us; speedup 1.0000x reference)
//
#include <hip/hip_runtime.h>

// Problem constants
#define NB      32      // batch
#define INF     128     // in_flt
#define NPIX    64      // N
#define TSP     16      // t
#define OUTF    32      // out_flt
#define FF      16      // intermediate features
#define D_IN    768     // 3*t*t
#define D_OUT   8192    // out_flt*t*t
#define NCOL    (D_OUT*FF)   // 131072
#define OUTCH   160     // in_flt + out_flt
#define BSTRIDE 655360  // 160*64*64 floats per batch in d_out
#define KCH     4       // k-chunks
#define KROWS   192     // rows per k-chunk
#define NBNCOL  ((size_t)NB*NCOL)

// ===== DIAGNOSTIC ROUND: every kernel amplified past the ~230us fill wall =====
// R6..R12: five structurally different k2's all land at total 180-187us.
// k1/k3/k4 have NEVER been measured (attribution was subtraction vs models).
// Reps are idempotent; LDS reuse across reps fenced with barriers.

// K1 x12: fused strided conv + x->out concat copy.
__global__ __launch_bounds__(256) void k1_conv_copy(
    const float* __restrict__ x, const float* __restrict__ wc,
    float* __restrict__ out, float* __restrict__ At)
{
    __shared__ float sW[3*128*16];     // 24 KB
    __shared__ float sP[16][16][3];
    const int b   = blockIdx.x >> 4;
    const int oi  = blockIdx.x & 15;
    const int tid = threadIdx.x;
    for (int idx = tid; idx < 6144; idx += 256) sW[idx] = wc[idx];
    __syncthreads();
    const int icg = tid >> 4;
    const int j   = tid & 15;
    for (int rep = 0; rep < 12; ++rep) {
        float a0 = 0.f, a1 = 0.f, a2 = 0.f;
        for (int ic8 = 0; ic8 < 8; ++ic8) {
            const int ic = icg*8 + ic8;
            #pragma unroll
            for (int ki = 0; ki < 4; ++ki) {
                const int row = 4*oi + ki;
                const float4 xv = *(const float4*)(x + ((size_t)(b*INF+ic)*NPIX + row)*NPIX + 4*j);
                *(float4*)(out + ((size_t)(b*OUTCH+ic)*NPIX + row)*NPIX + 4*j) = xv;
                const float* w0 = sW + ((0*INF+ic)*4 + ki)*4;
                const float* w1 = sW + ((1*INF+ic)*4 + ki)*4;
                const float* w2 = sW + ((2*INF+ic)*4 + ki)*4;
                a0 += xv.x*w0[0] + xv.y*w0[1] + xv.z*w0[2] + xv.w*w0[3];
                a1 += xv.x*w1[0] + xv.y*w1[1] + xv.z*w1[2] + xv.w*w1[3];
                a2 += xv.x*w2[0] + xv.y*w2[1] + xv.z*w2[2] + xv.w*w2[3];
            }
        }
        sP[icg][j][0] = a0; sP[icg][j][1] = a1; sP[icg][j][2] = a2;
        __syncthreads();
        if (tid < 48) {
            const int c3 = tid >> 4, jj = tid & 15;
            float s = 0.f;
            #pragma unroll
            for (int g = 0; g < 16; ++g) s += sP[g][jj][c3];
            At[(c3*256 + oi*16 + jj)*32 + b] = s;
        }
        __syncthreads();   // sP reuse fence
    }
}

// K2 v12 x4: linear T-streaming (unchanged inside rep).
__global__ __launch_bounds__(256, 2) void k2_gemm(
    const float* __restrict__ At, const float* __restrict__ Tm,
    float* __restrict__ Mp)
{
    __shared__ float sA[KROWS*32];     // 24 KB, staged ONCE (no rep hazard)
    const int tid = threadIdx.x;
    const int kc  = blockIdx.x >> 7;
    const int cc  = blockIdx.x & 127;
    const int k0g = kc * KROWS;
    {
        const float4* src = (const float4*)(At + k0g*32);
        float4* dst = (float4*)sA;
        #pragma unroll
        for (int i = 0; i < 6; ++i) dst[tid + i*256] = src[tid + i*256];
    }
    __syncthreads();

    const float* tp = Tm + (size_t)k0g*NCOL + cc*1024 + tid*4;

    for (int rep = 0; rep < 4; ++rep) {
        float acc[32][4];
        #pragma unroll
        for (int i = 0; i < 32; ++i)
            #pragma unroll
            for (int j = 0; j < 4; ++j) acc[i][j] = 0.f;

#define TLD(KK) (*(const float4*)(tp + (size_t)(KK)*NCOL))
#define FMG(G, AV, T4) { \
  acc[(G)*4+0][0]+=AV.x*T4.x; acc[(G)*4+0][1]+=AV.x*T4.y; acc[(G)*4+0][2]+=AV.x*T4.z; acc[(G)*4+0][3]+=AV.x*T4.w; \
  acc[(G)*4+1][0]+=AV.y*T4.x; acc[(G)*4+1][1]+=AV.y*T4.y; acc[(G)*4+1][2]+=AV.y*T4.z; acc[(G)*4+1][3]+=AV.y*T4.w; \
  acc[(G)*4+2][0]+=AV.z*T4.x; acc[(G)*4+2][1]+=AV.z*T4.y; acc[(G)*4+2][2]+=AV.z*T4.z; acc[(G)*4+2][3]+=AV.z*T4.w; \
  acc[(G)*4+3][0]+=AV.w*T4.x; acc[(G)*4+3][1]+=AV.w*T4.y; acc[(G)*4+3][2]+=AV.w*T4.z; acc[(G)*4+3][3]+=AV.w*T4.w; }
#define ALD(J) \
    const float* ar = sA + (k0+(J))*32; \
    const float4 a0 = *(const float4*)(ar +  0); \
    const float4 a1 = *(const float4*)(ar +  4); \
    const float4 a2 = *(const float4*)(ar +  8); \
    const float4 a3 = *(const float4*)(ar + 12); \
    const float4 a4 = *(const float4*)(ar + 16); \
    const float4 a5 = *(const float4*)(ar + 20); \
    const float4 a6 = *(const float4*)(ar + 24); \
    const float4 a7 = *(const float4*)(ar + 28);
#define STEP(J, RT) { ALD(J) \
    FMG(0,a0,RT) FMG(1,a1,RT) FMG(2,a2,RT) FMG(3,a3,RT) \
    FMG(4,a4,RT) FMG(5,a5,RT) FMG(6,a6,RT) FMG(7,a7,RT) \
    RT = TLD(k0 + 4 + (J)); }
#define STEPE(J, RT) { ALD(J) \
    FMG(0,a0,RT) FMG(1,a1,RT) FMG(2,a2,RT) FMG(3,a3,RT) \
    FMG(4,a4,RT) FMG(5,a5,RT) FMG(6,a6,RT) FMG(7,a7,RT) }

        float4 r0=TLD(0), r1=TLD(1), r2=TLD(2), r3=TLD(3);
        int k0 = 0;
        for (; k0 < KROWS - 4; k0 += 4) {
            STEP(0, r0) STEP(1, r1) STEP(2, r2) STEP(3, r3)
        }
        STEPE(0, r0) STEPE(1, r1) STEPE(2, r2) STEPE(3, r3)
#undef STEPE
#undef STEP
#undef ALD
#undef FMG
#undef TLD

        float* mp = Mp + (size_t)kc*NBNCOL + cc*1024 + tid*4;
        #pragma unroll
        for (int bb = 0; bb < 32; ++bb)
            *(float4*)(mp + (size_t)bb*NCOL) =
                make_float4(acc[bb][0], acc[bb][1], acc[bb][2], acc[bb][3]);
    }
}

// K3 x14: pairwise L1 + exp; merges 4 k-partials on load.
__global__ __launch_bounds__(256) void k3_pairs(
    const float* __restrict__ Mp, float* __restrict__ outS)
{
    extern __shared__ float sM[];
    const int tid = threadIdx.x;
    const int dd0 = blockIdx.x * 32;
    for (int rep = 0; rep < 14; ++rep) {
        for (int idx = tid; idx < 32*32*16; idx += 256) {
            const int i = idx >> 9, rem = idx & 511, d = rem >> 4, f = rem & 15;
            const size_t off = (size_t)i*NCOL + (size_t)dd0*16 + rem;
            sM[(i*32 + d)*17 + f] = (Mp[off] + Mp[off + NBNCOL])
                                  + (Mp[off + 2*NBNCOL] + Mp[off + 3*NBNCOL]);
        }
        __syncthreads();
        const int j = tid >> 3;
        for (int q = 0; q < 4; ++q) {
            const int d = (tid & 7) + q*8;
            float mj[16];
            const float* pj = sM + (j*32 + d)*17;
            #pragma unroll
            for (int f = 0; f < 16; ++f) mj[f] = pj[f];
            float acc = 0.f;
            for (int i = 0; i < 32; ++i) {
                const float* pi = sM + (i*32 + d)*17;
                float dist = 0.f;
                #pragma unroll
                for (int f = 0; f < 16; ++f) dist += fabsf(pi[f] - mj[f]);
                acc += __expf(-dist);
            }
            outS[(size_t)j*D_OUT + dd0 + d] = acc - 1.0f;
        }
        __syncthreads();   // sM reuse fence
    }
}

// K4 x40: ConvTranspose2d, stride==kernel.
__global__ __launch_bounds__(256) void k4_deconv(
    const float* __restrict__ outS, const float* __restrict__ wd,
    float* __restrict__ out)
{
    __shared__ float sO[32*256];
    __shared__ float sWd[32*16];
    const int b   = blockIdx.x >> 5;
    const int oc  = blockIdx.x & 31;
    const int tid = threadIdx.x;
    for (int rep = 0; rep < 40; ++rep) {
        for (int idx = tid; idx < 8192; idx += 256) sO[idx] = outS[(size_t)b*D_OUT + idx];
        for (int idx = tid; idx < 512; idx += 256) {
            const int ic = idx >> 4, r = idx & 15;
            sWd[idx] = wd[((ic*32 + oc) << 4) + r];
        }
        __syncthreads();
        float* ob = out + (size_t)b*BSTRIDE + (size_t)(128 + oc)*4096;
        for (int s = 0; s < 16; ++s) {
            const int p  = tid + (s << 8);
            const int i  = p >> 6, jc = p & 63;
            const int si = i >> 2, ki = i & 3, sj = jc >> 2, kj = jc & 3;
            float acc = 0.f;
            #pragma unroll
            for (int ic = 0; ic < 32; ++ic)
                acc += sO[ic*256 + si*16 + sj] * sWd[ic*16 + ki*4 + kj];
            ob[p] = acc;
        }
        __syncthreads();   // sO/sWd reuse fence
    }
}

extern "C" void kernel_launch(void* const* d_in, const int* in_sizes, int n_in,
                              void* d_out, int out_size, void* d_ws, size_t ws_size,
                              hipStream_t stream) {
    const float* x  = (const float*)d_in[0];
    const float* wc = (const float*)d_in[1];
    const float* Tm = (const float*)d_in[2];
    const float* wd = (const float*)d_in[3];
    float* out  = (float*)d_out;
    float* At   = (float*)d_ws;                        // 96 KB @ 0
    float* Mp   = (float*)((char*)d_ws + (1 << 20));   // 67 MB @ 1 MB
    float* outS = (float*)((char*)d_ws + (72 << 20));  // 1 MB @ 72 MB

    k1_conv_copy<<<NB*TSP, 256, 0, stream>>>(x, wc, out, At);                   // x12
    k2_gemm    <<<KCH*128, 256, 0, stream>>>(At, Tm, Mp);                       // x4
    k3_pairs   <<<D_OUT/32, 256, 32*32*17*sizeof(float), stream>>>(Mp, outS);   // x14
    k4_deconv  <<<NB*OUTF, 256, 0, stream>>>(outS, wd, out);                    // x40
}

// Round 14
// 366.858 us; speedup vs baseline: 4.3739x; 4.3739x over previous
//
#include <hip/hip_runtime.h>

// Problem constants
#define NB      32      // batch
#define INF     128     // in_flt
#define NPIX    64      // N
#define TSP     16      // t
#define OUTF    32      // out_flt
#define FF      16      // intermediate features
#define D_IN    768     // 3*t*t
#define D_OUT   8192    // out_flt*t*t
#define NCOL    (D_OUT*FF)   // 131072
#define OUTCH   160     // in_flt + out_flt
#define BSTRIDE 655360  // 160*64*64 floats per batch in d_out
#define KCH     4       // k-chunks
#define KROWS   192     // rows per k-chunk
#define NBNCOL  ((size_t)NB*NCOL)

// K1: fused strided conv (128ch,4x4,stride4 -> 3ch) + x->out concat copy.
__global__ __launch_bounds__(256) void k1_conv_copy(
    const float* __restrict__ x, const float* __restrict__ wc,
    float* __restrict__ out, float* __restrict__ At)
{
    __shared__ float sW[3*128*16];     // 24 KB
    __shared__ float sP[16][16][3];
    const int b   = blockIdx.x >> 4;
    const int oi  = blockIdx.x & 15;
    const int tid = threadIdx.x;
    for (int idx = tid; idx < 6144; idx += 256) sW[idx] = wc[idx];
    __syncthreads();
    const int icg = tid >> 4;
    const int j   = tid & 15;
    float a0 = 0.f, a1 = 0.f, a2 = 0.f;
    for (int ic8 = 0; ic8 < 8; ++ic8) {
        const int ic = icg*8 + ic8;
        #pragma unroll
        for (int ki = 0; ki < 4; ++ki) {
            const int row = 4*oi + ki;
            const float4 xv = *(const float4*)(x + ((size_t)(b*INF+ic)*NPIX + row)*NPIX + 4*j);
            *(float4*)(out + ((size_t)(b*OUTCH+ic)*NPIX + row)*NPIX + 4*j) = xv;
            const float* w0 = sW + ((0*INF+ic)*4 + ki)*4;
            const float* w1 = sW + ((1*INF+ic)*4 + ki)*4;
            const float* w2 = sW + ((2*INF+ic)*4 + ki)*4;
            a0 += xv.x*w0[0] + xv.y*w0[1] + xv.z*w0[2] + xv.w*w0[3];
            a1 += xv.x*w1[0] + xv.y*w1[1] + xv.z*w1[2] + xv.w*w1[3];
            a2 += xv.x*w2[0] + xv.y*w2[1] + xv.z*w2[2] + xv.w*w2[3];
        }
    }
    sP[icg][j][0] = a0; sP[icg][j][1] = a1; sP[icg][j][2] = a2;
    __syncthreads();
    if (tid < 48) {
        const int c3 = tid >> 4, jj = tid & 15;
        float s = 0.f;
        #pragma unroll
        for (int g = 0; g < 16; ++g) s += sP[g][jj][c3];
        At[(c3*256 + oi*16 + jj)*32 + b] = s;
    }
}

// K2 v13: SPILL FIX. R13 counters proved v11/v12 spilled (VGPR_Count=128
// vs ~190 live: acc128+A32+ring16+addr; WRITE_SIZE 915MB vs 268MB Mp =
// ~650MB scratch traffic). v13: A read DIRECTLY from global At at
// wave-uniform (blockIdx/loop-derived = SGPR-arithmetic) addresses ->
// s_load_dwordx16 on the K$/L2 path: A lives in SGPRs (v_fmac s-operand),
// no LDS at all (also removes the 61us/rep ds_read pipe floor), VGPR ~150
// -> no spill at __launch_bounds__(256) (2 waves/SIMD unchanged).
// x3 inner reps THIS ROUND ONLY for counter visibility (>230us fill wall).
__global__ __launch_bounds__(256) void k2_gemm(
    const float* __restrict__ At, const float* __restrict__ Tm,
    float* __restrict__ Mp)
{
    const int tid = threadIdx.x;
    const int kc  = blockIdx.x >> 7;   // 0..3   (SGPR)
    const int cc  = blockIdx.x & 127;  // 0..127 (SGPR)
    const int k0g = kc * KROWS;

    const float* tp = Tm + (size_t)k0g*NCOL + cc*1024 + tid*4;
    const float* ap = At + k0g*32;     // uniform -> scalar loads

    for (int rep = 0; rep < 3; ++rep) {
        float acc[32][4];
        #pragma unroll
        for (int i = 0; i < 32; ++i)
            #pragma unroll
            for (int j = 0; j < 4; ++j) acc[i][j] = 0.f;

#define TLD(KK) (*(const float4*)(tp + (size_t)(KK)*NCOL))
#define FMG(G, AV, T4) { \
  acc[(G)*4+0][0]+=AV.x*T4.x; acc[(G)*4+0][1]+=AV.x*T4.y; acc[(G)*4+0][2]+=AV.x*T4.z; acc[(G)*4+0][3]+=AV.x*T4.w; \
  acc[(G)*4+1][0]+=AV.y*T4.x; acc[(G)*4+1][1]+=AV.y*T4.y; acc[(G)*4+1][2]+=AV.y*T4.z; acc[(G)*4+1][3]+=AV.y*T4.w; \
  acc[(G)*4+2][0]+=AV.z*T4.x; acc[(G)*4+2][1]+=AV.z*T4.y; acc[(G)*4+2][2]+=AV.z*T4.z; acc[(G)*4+2][3]+=AV.z*T4.w; \
  acc[(G)*4+3][0]+=AV.w*T4.x; acc[(G)*4+3][1]+=AV.w*T4.y; acc[(G)*4+3][2]+=AV.w*T4.z; acc[(G)*4+3][3]+=AV.w*T4.w; }
#define ALD(J) \
    const float* ar = ap + (k0+(J))*32;          /* uniform (SGPR) addr */ \
    const float4 a0 = *(const float4*)(ar +  0); \
    const float4 a1 = *(const float4*)(ar +  4); \
    const float4 a2 = *(const float4*)(ar +  8); \
    const float4 a3 = *(const float4*)(ar + 12); \
    const float4 a4 = *(const float4*)(ar + 16); \
    const float4 a5 = *(const float4*)(ar + 20); \
    const float4 a6 = *(const float4*)(ar + 24); \
    const float4 a7 = *(const float4*)(ar + 28);
#define STEP(J, RT) { ALD(J) \
    FMG(0,a0,RT) FMG(1,a1,RT) FMG(2,a2,RT) FMG(3,a3,RT) \
    FMG(4,a4,RT) FMG(5,a5,RT) FMG(6,a6,RT) FMG(7,a7,RT) \
    RT = TLD(k0 + 4 + (J)); }
#define STEPE(J, RT) { ALD(J) \
    FMG(0,a0,RT) FMG(1,a1,RT) FMG(2,a2,RT) FMG(3,a3,RT) \
    FMG(4,a4,RT) FMG(5,a5,RT) FMG(6,a6,RT) FMG(7,a7,RT) }

        float4 r0=TLD(0), r1=TLD(1), r2=TLD(2), r3=TLD(3);
        int k0 = 0;
        for (; k0 < KROWS - 4; k0 += 4) {
            STEP(0, r0) STEP(1, r1) STEP(2, r2) STEP(3, r3)
        }
        // epilogue: k0 == KROWS-4, consume only
        STEPE(0, r0) STEPE(1, r1) STEPE(2, r2) STEPE(3, r3)
#undef STEPE
#undef STEP
#undef ALD
#undef FMG
#undef TLD

        float* mp = Mp + (size_t)kc*NBNCOL + cc*1024 + tid*4;
        #pragma unroll
        for (int bb = 0; bb < 32; ++bb)
            *(float4*)(mp + (size_t)bb*NCOL) =
                make_float4(acc[bb][0], acc[bb][1], acc[bb][2], acc[bb][3]);
    }
}

// K3: out[j,d] = sum_i exp(-sum_f |M[i,d,f]-M[j,d,f]|) - 1.
// Merges the 4 k-chunk partials while loading into LDS.
__global__ __launch_bounds__(256) void k3_pairs(
    const float* __restrict__ Mp, float* __restrict__ outS)
{
    extern __shared__ float sM[];      // 32*32*17 floats
    const int tid = threadIdx.x;
    const int dd0 = blockIdx.x * 32;
    for (int idx = tid; idx < 32*32*16; idx += 256) {
        const int i = idx >> 9, rem = idx & 511, d = rem >> 4, f = rem & 15;
        const size_t off = (size_t)i*NCOL + (size_t)dd0*16 + rem;
        sM[(i*32 + d)*17 + f] = (Mp[off] + Mp[off + NBNCOL])
                              + (Mp[off + 2*NBNCOL] + Mp[off + 3*NBNCOL]);
    }
    __syncthreads();
    const int j = tid >> 3;
    for (int q = 0; q < 4; ++q) {
        const int d = (tid & 7) + q*8;
        float mj[16];
        const float* pj = sM + (j*32 + d)*17;
        #pragma unroll
        for (int f = 0; f < 16; ++f) mj[f] = pj[f];
        float acc = 0.f;
        for (int i = 0; i < 32; ++i) {
            const float* pi = sM + (i*32 + d)*17;
            float dist = 0.f;
            #pragma unroll
            for (int f = 0; f < 16; ++f) dist += fabsf(pi[f] - mj[f]);
            acc += __expf(-dist);
        }
        outS[(size_t)j*D_OUT + dd0 + d] = acc - 1.0f;
    }
}

// K4: ConvTranspose2d, stride==kernel -> no overlap.
__global__ __launch_bounds__(256) void k4_deconv(
    const float* __restrict__ outS, const float* __restrict__ wd,
    float* __restrict__ out)
{
    __shared__ float sO[32*256];
    __shared__ float sWd[32*16];
    const int b   = blockIdx.x >> 5;
    const int oc  = blockIdx.x & 31;
    const int tid = threadIdx.x;
    for (int idx = tid; idx < 8192; idx += 256) sO[idx] = outS[(size_t)b*D_OUT + idx];
    for (int idx = tid; idx < 512; idx += 256) {
        const int ic = idx >> 4, r = idx & 15;
        sWd[idx] = wd[((ic*32 + oc) << 4) + r];
    }
    __syncthreads();
    float* ob = out + (size_t)b*BSTRIDE + (size_t)(128 + oc)*4096;
    for (int s = 0; s < 16; ++s) {
        const int p  = tid + (s << 8);
        const int i  = p >> 6, jc = p & 63;
        const int si = i >> 2, ki = i & 3, sj = jc >> 2, kj = jc & 3;
        float acc = 0.f;
        #pragma unroll
        for (int ic = 0; ic < 32; ++ic)
            acc += sO[ic*256 + si*16 + sj] * sWd[ic*16 + ki*4 + kj];
        ob[p] = acc;
    }
}

extern "C" void kernel_launch(void* const* d_in, const int* in_sizes, int n_in,
                              void* d_out, int out_size, void* d_ws, size_t ws_size,
                              hipStream_t stream) {
    const float* x  = (const float*)d_in[0];
    const float* wc = (const float*)d_in[1];
    const float* Tm = (const float*)d_in[2];
    const float* wd = (const float*)d_in[3];
    float* out  = (float*)d_out;
    float* At   = (float*)d_ws;                        // 96 KB @ 0
    float* Mp   = (float*)((char*)d_ws + (1 << 20));   // 67 MB @ 1 MB
    float* outS = (float*)((char*)d_ws + (72 << 20));  // 1 MB @ 72 MB

    k1_conv_copy<<<NB*TSP, 256, 0, stream>>>(x, wc, out, At);                   // 512 blocks
    k2_gemm    <<<KCH*128, 256, 0, stream>>>(At, Tm, Mp);                       // 512 blocks, x3
    k3_pairs   <<<D_OUT/32, 256, 32*32*17*sizeof(float), stream>>>(Mp, outS);   // 256 blocks
    k4_deconv  <<<NB*OUTF, 256, 0, stream>>>(outS, wd, out);                    // 1024 blocks
}

// Round 15
// 174.890 us; speedup vs baseline: 9.1750x; 2.0977x over previous
//
#include <hip/hip_runtime.h>

// Problem constants
#define NB      32      // batch
#define INF     128     // in_flt
#define NPIX    64      // N
#define TSP     16      // t
#define OUTF    32      // out_flt
#define FF      16      // intermediate features
#define D_IN    768     // 3*t*t
#define D_OUT   8192    // out_flt*t*t
#define NCOL    (D_OUT*FF)   // 131072
#define OUTCH   160     // in_flt + out_flt
#define BSTRIDE 655360  // 160*64*64 floats per batch in d_out
#define KCH     4       // k-chunks
#define KROWS   192     // rows per k-chunk
#define NBNCOL  ((size_t)NB*NCOL)

// K1: fused strided conv (128ch,4x4,stride4 -> 3ch) + x->out concat copy.
__global__ __launch_bounds__(256) void k1_conv_copy(
    const float* __restrict__ x, const float* __restrict__ wc,
    float* __restrict__ out, float* __restrict__ At)
{
    __shared__ float sW[3*128*16];     // 24 KB
    __shared__ float sP[16][16][3];
    const int b   = blockIdx.x >> 4;
    const int oi  = blockIdx.x & 15;
    const int tid = threadIdx.x;
    for (int idx = tid; idx < 6144; idx += 256) sW[idx] = wc[idx];
    __syncthreads();
    const int icg = tid >> 4;
    const int j   = tid & 15;
    float a0 = 0.f, a1 = 0.f, a2 = 0.f;
    for (int ic8 = 0; ic8 < 8; ++ic8) {
        const int ic = icg*8 + ic8;
        #pragma unroll
        for (int ki = 0; ki < 4; ++ki) {
            const int row = 4*oi + ki;
            const float4 xv = *(const float4*)(x + ((size_t)(b*INF+ic)*NPIX + row)*NPIX + 4*j);
            *(float4*)(out + ((size_t)(b*OUTCH+ic)*NPIX + row)*NPIX + 4*j) = xv;
            const float* w0 = sW + ((0*INF+ic)*4 + ki)*4;
            const float* w1 = sW + ((1*INF+ic)*4 + ki)*4;
            const float* w2 = sW + ((2*INF+ic)*4 + ki)*4;
            a0 += xv.x*w0[0] + xv.y*w0[1] + xv.z*w0[2] + xv.w*w0[3];
            a1 += xv.x*w1[0] + xv.y*w1[1] + xv.z*w1[2] + xv.w*w1[3];
            a2 += xv.x*w2[0] + xv.y*w2[1] + xv.z*w2[2] + xv.w*w2[3];
        }
    }
    sP[icg][j][0] = a0; sP[icg][j][1] = a1; sP[icg][j][2] = a2;
    __syncthreads();
    if (tid < 48) {
        const int c3 = tid >> 4, jj = tid & 15;
        float s = 0.f;
        #pragma unroll
        for (int g = 0; g < 16; ++g) s += sP[g][jj][c3];
        At[(c3*256 + oi*16 + jj)*32 + b] = s;
    }
}

// K2 v14: BATCH-SPLIT FOR TLP. R14 counters: spill gone (VGPR 112, WRITE
// 67MB) but warm==cold at 106us/rep, VALUBusy 42% -> ~800cyc/step exposed
// s_load latency with only 2 waves/SIMD (both stall in lockstep; v13
// dropped the A-pipeline). v14: block=512thr = 2 batch-halves x 256
// col-thr (SAME 1024 cols; 2nd half's T re-read hits L1 in-block).
// acc[16][4]=64 VGPR -> no spill under launch_bounds(512,4) cap 128;
// grid 512 -> 2 blocks/CU = 4 waves/SIMD: wave interleave covers the
// s_load latency; aggregate VALU/SIMD unchanged. bh readfirstlane'd:
// bit-level uniformity of tid>>8 is NOT tracked by divergence analysis,
// and A must stay on the scalar path (R4: A in vmcnt queue drains T ring).
__global__ __launch_bounds__(512, 4) void k2_gemm(
    const float* __restrict__ At, const float* __restrict__ Tm,
    float* __restrict__ Mp)
{
    const int tid = threadIdx.x;
    const int kc  = blockIdx.x >> 7;   // 0..3   (SGPR)
    const int cc  = blockIdx.x & 127;  // 0..127 (SGPR)
    const int k0g = kc * KROWS;
    const int bh  = __builtin_amdgcn_readfirstlane(tid >> 8);  // batch half
    const int ct  = tid & 255;                                 // col-thread

    const float* tp = Tm + (size_t)k0g*NCOL + cc*1024 + ct*4;
    const float* ap = At + k0g*32 + bh*16;   // uniform -> s_load path

    float acc[16][4];
    #pragma unroll
    for (int i = 0; i < 16; ++i)
        #pragma unroll
        for (int j = 0; j < 4; ++j) acc[i][j] = 0.f;

#define TLD(KK) (*(const float4*)(tp + (size_t)(KK)*NCOL))
#define FMG(G, AV, T4) { \
  acc[(G)*4+0][0]+=AV.x*T4.x; acc[(G)*4+0][1]+=AV.x*T4.y; acc[(G)*4+0][2]+=AV.x*T4.z; acc[(G)*4+0][3]+=AV.x*T4.w; \
  acc[(G)*4+1][0]+=AV.y*T4.x; acc[(G)*4+1][1]+=AV.y*T4.y; acc[(G)*4+1][2]+=AV.y*T4.z; acc[(G)*4+1][3]+=AV.y*T4.w; \
  acc[(G)*4+2][0]+=AV.z*T4.x; acc[(G)*4+2][1]+=AV.z*T4.y; acc[(G)*4+2][2]+=AV.z*T4.z; acc[(G)*4+2][3]+=AV.z*T4.w; \
  acc[(G)*4+3][0]+=AV.w*T4.x; acc[(G)*4+3][1]+=AV.w*T4.y; acc[(G)*4+3][2]+=AV.w*T4.z; acc[(G)*4+3][3]+=AV.w*T4.w; }
#define ALD(J) \
    const float* ar = ap + (k0+(J))*32;          /* uniform (SGPR) addr */ \
    const float4 a0 = *(const float4*)(ar +  0); \
    const float4 a1 = *(const float4*)(ar +  4); \
    const float4 a2 = *(const float4*)(ar +  8); \
    const float4 a3 = *(const float4*)(ar + 12);
#define STEP(J, RT) { ALD(J) \
    FMG(0,a0,RT) FMG(1,a1,RT) FMG(2,a2,RT) FMG(3,a3,RT) \
    RT = TLD(k0 + 4 + (J)); }
#define STEPE(J, RT) { ALD(J) \
    FMG(0,a0,RT) FMG(1,a1,RT) FMG(2,a2,RT) FMG(3,a3,RT) }

    float4 r0=TLD(0), r1=TLD(1), r2=TLD(2), r3=TLD(3);
    int k0 = 0;
    for (; k0 < KROWS - 4; k0 += 4) {
        STEP(0, r0) STEP(1, r1) STEP(2, r2) STEP(3, r3)
    }
    // epilogue: k0 == KROWS-4, consume only
    STEPE(0, r0) STEPE(1, r1) STEPE(2, r2) STEPE(3, r3)
#undef STEPE
#undef STEP
#undef ALD
#undef FMG
#undef TLD

    float* mp = Mp + (size_t)kc*NBNCOL + (size_t)(bh*16)*NCOL + cc*1024 + ct*4;
    #pragma unroll
    for (int bb = 0; bb < 16; ++bb)
        *(float4*)(mp + (size_t)bb*NCOL) =
            make_float4(acc[bb][0], acc[bb][1], acc[bb][2], acc[bb][3]);
}

// K3: out[j,d] = sum_i exp(-sum_f |M[i,d,f]-M[j,d,f]|) - 1.
// Merges the 4 k-chunk partials while loading into LDS.
__global__ __launch_bounds__(256) void k3_pairs(
    const float* __restrict__ Mp, float* __restrict__ outS)
{
    extern __shared__ float sM[];      // 32*32*17 floats
    const int tid = threadIdx.x;
    const int dd0 = blockIdx.x * 32;
    for (int idx = tid; idx < 32*32*16; idx += 256) {
        const int i = idx >> 9, rem = idx & 511, d = rem >> 4, f = rem & 15;
        const size_t off = (size_t)i*NCOL + (size_t)dd0*16 + rem;
        sM[(i*32 + d)*17 + f] = (Mp[off] + Mp[off + NBNCOL])
                              + (Mp[off + 2*NBNCOL] + Mp[off + 3*NBNCOL]);
    }
    __syncthreads();
    const int j = tid >> 3;
    for (int q = 0; q < 4; ++q) {
        const int d = (tid & 7) + q*8;
        float mj[16];
        const float* pj = sM + (j*32 + d)*17;
        #pragma unroll
        for (int f = 0; f < 16; ++f) mj[f] = pj[f];
        float acc = 0.f;
        for (int i = 0; i < 32; ++i) {
            const float* pi = sM + (i*32 + d)*17;
            float dist = 0.f;
            #pragma unroll
            for (int f = 0; f < 16; ++f) dist += fabsf(pi[f] - mj[f]);
            acc += __expf(-dist);
        }
        outS[(size_t)j*D_OUT + dd0 + d] = acc - 1.0f;
    }
}

// K4: ConvTranspose2d, stride==kernel -> no overlap.
__global__ __launch_bounds__(256) void k4_deconv(
    const float* __restrict__ outS, const float* __restrict__ wd,
    float* __restrict__ out)
{
    __shared__ float sO[32*256];
    __shared__ float sWd[32*16];
    const int b   = blockIdx.x >> 5;
    const int oc  = blockIdx.x & 31;
    const int tid = threadIdx.x;
    for (int idx = tid; idx < 8192; idx += 256) sO[idx] = outS[(size_t)b*D_OUT + idx];
    for (int idx = tid; idx < 512; idx += 256) {
        const int ic = idx >> 4, r = idx & 15;
        sWd[idx] = wd[((ic*32 + oc) << 4) + r];
    }
    __syncthreads();
    float* ob = out + (size_t)b*BSTRIDE + (size_t)(128 + oc)*4096;
    for (int s = 0; s < 16; ++s) {
        const int p  = tid + (s << 8);
        const int i  = p >> 6, jc = p & 63;
        const int si = i >> 2, ki = i & 3, sj = jc >> 2, kj = jc & 3;
        float acc = 0.f;
        #pragma unroll
        for (int ic = 0; ic < 32; ++ic)
            acc += sO[ic*256 + si*16 + sj] * sWd[ic*16 + ki*4 + kj];
        ob[p] = acc;
    }
}

extern "C" void kernel_launch(void* const* d_in, const int* in_sizes, int n_in,
                              void* d_out, int out_size, void* d_ws, size_t ws_size,
                              hipStream_t stream) {
    const float* x  = (const float*)d_in[0];
    const float* wc = (const float*)d_in[1];
    const float* Tm = (const float*)d_in[2];
    const float* wd = (const float*)d_in[3];
    float* out  = (float*)d_out;
    float* At   = (float*)d_ws;                        // 96 KB @ 0
    float* Mp   = (float*)((char*)d_ws + (1 << 20));   // 67 MB @ 1 MB
    float* outS = (float*)((char*)d_ws + (72 << 20));  // 1 MB @ 72 MB

    k1_conv_copy<<<NB*TSP, 256, 0, stream>>>(x, wc, out, At);                   // 512 blocks
    k2_gemm    <<<KCH*128, 512, 0, stream>>>(At, Tm, Mp);                       // 512 blocks x 512 thr
    k3_pairs   <<<D_OUT/32, 256, 32*32*17*sizeof(float), stream>>>(Mp, outS);   // 256 blocks
    k4_deconv  <<<NB*OUTF, 256, 0, stream>>>(outS, wd, out);                    // 1024 blocks
}